// Round 5
// baseline (1523.480 us; speedup 1.0000x reference)
//
#include <hip/hip_runtime.h>
#include <hip/hip_bf16.h>
#include <math.h>

typedef __attribute__((ext_vector_type(8))) __bf16 bf16x8;
typedef __attribute__((ext_vector_type(4))) float f32x4;

#define NPTS   131072
#define TBL    32768
#define MT     32
#define TWO_PI 6.28318530717958647692f

// R10: resubmission of R9 (bench died to container-level infra failure, which
// is not evidence about kernel content). R5 scaffold (last known-good) plus:
//   1. sinf -> __sinf (hardware v_sin_f32 via OCML native): ~416 sin calls per
//      thread were libm with full range reduction (~25 instr each), the
//      largest single VALU consumer. Args are O(1-5) rad -> native precision
//      ~1e-5, invisible vs the 7.7e-2 threshold.
//   2. __launch_bounds__(256,3): 100 VGPR / 37.9KB LDS fits 3 blocks/CU; the
//      old (256,2) pinned occupancy at 23.6% for no reason.
// Prep-table path (R6/R7/R8) remains parked: numerically wrong twice, root
// cause not identifiable from here.

__global__ __launch_bounds__(256, 3) void ffb_main(
    const float* __restrict__ in_pos, const float* __restrict__ table,
    const float* __restrict__ ffnA, const float* __restrict__ W0,
    const float* __restrict__ b0, const float* __restrict__ Ws,
    const float* __restrict__ bs, const float* __restrict__ Wh,
    const float* __restrict__ bh, float* __restrict__ out)
{
    __shared__ __align__(16) float xbuf[MT][260];   // fp32 x tile (R3-proven)
    __shared__ __align__(16) float gf[4][MT][8];
    __shared__ float ptile[MT][3];

    const int tid   = threadIdx.x;
    const int wave  = tid >> 6;
    const int lane  = tid & 63;
    const int laneN = lane & 15;      // A row m / B col n / D col
    const int kb    = lane >> 4;      // k-octet / D row-quad
    const int m0    = blockIdx.x * MT;

    if (tid < MT * 3) ((float*)ptile)[tid] = in_pos[m0 * 3 + tid];
    __syncthreads();

    // ---- hash-grid encode (R5 verbatim)
    if (tid < 128) {
        const int l = tid >> 5, m = tid & 31;
        const float px = ptile[m][0], py = ptile[m][1], pz = ptile[m][2];
        const float res = (float)(16 << l);
        const float fx = (px + 1.0f) * 0.5f * res;
        const float fy = (py + 1.0f) * 0.5f * res;
        const float fz = (pz + 1.0f) * 0.5f * res;
        const float f0x = floorf(fx), f0y = floorf(fy), f0z = floorf(fz);
        const float frx = fx - f0x, fry = fy - f0y, frz = fz - f0z;
        const unsigned ux = (unsigned)f0x, uy = (unsigned)f0y, uz = (unsigned)f0z;
        float acc[8];
#pragma unroll
        for (int f = 0; f < 8; ++f) acc[f] = 0.0f;
#pragma unroll
        for (int c = 0; c < 8; ++c) {
            const unsigned cx = ux + ((c >> 2) & 1);
            const unsigned cy = uy + ((c >> 1) & 1);
            const unsigned cz = uz + (c & 1);
            const unsigned id = (cx * 1u ^ cy * 2654435761u ^ cz * 805459861u) & (TBL - 1);
            const float4* tp = (const float4*)(table + ((size_t)(l * TBL + id) << 3));
            const float4 t0 = tp[0], t1 = tp[1];
            const float wx = (c & 4) ? frx : 1.0f - frx;
            const float wy = (c & 2) ? fry : 1.0f - fry;
            const float wz = (c & 1) ? frz : 1.0f - frz;
            const float w = wx * wy * wz;
            acc[0] += w * t0.x; acc[1] += w * t0.y; acc[2] += w * t0.z; acc[3] += w * t0.w;
            acc[4] += w * t1.x; acc[5] += w * t1.y; acc[6] += w * t1.z; acc[7] += w * t1.w;
        }
#pragma unroll
        for (int f = 0; f < 8; ++f) gf[l][m][f] = acc[f];
    }

    // ---- layer 0 (R5 scaffold, fast sin)
    {
        const float w0 = W0[tid], w1 = W0[256 + tid], w2 = W0[512 + tid], bb = b0[tid];
#pragma unroll
        for (int m = 0; m < MT; ++m)
            xbuf[m][tid] = __sinf(ptile[m][0] * w0 + ptile[m][1] * w1 + ptile[m][2] * w2 + bb);
    }
    __syncthreads();

    f32x4 xout[2][4];
#pragma unroll
    for (int mt = 0; mt < 2; ++mt)
#pragma unroll
        for (int nt = 0; nt < 4; ++nt) xout[mt][nt] = (f32x4)0.0f;

    for (int l = 0; l < 4; ++l) {
        // ===== GEMM1: z1 = X @ Ws[l], split-bf16 MFMA, W from original layout
        f32x4 acc[2][4];
#pragma unroll
        for (int mt = 0; mt < 2; ++mt)
#pragma unroll
            for (int nt = 0; nt < 4; ++nt) acc[mt][nt] = (f32x4)0.0f;

        for (int kt = 0; kt < 8; ++kt) {
            const int k0 = kt * 32 + kb * 8;
            bf16x8 ah[2], al[2], wh8[4], wl8[4];
#pragma unroll
            for (int mt = 0; mt < 2; ++mt) {
                const f32x4 v0 = *(const f32x4*)&xbuf[mt * 16 + laneN][k0];
                const f32x4 v1 = *(const f32x4*)&xbuf[mt * 16 + laneN][k0 + 4];
                const float tmp[8] = {v0.x, v0.y, v0.z, v0.w, v1.x, v1.y, v1.z, v1.w};
#pragma unroll
                for (int j = 0; j < 8; ++j) {
                    const float v = tmp[j];
                    const __bf16 h = (__bf16)v;
                    ah[mt][j] = h;
                    al[mt][j] = (__bf16)(v - (float)h);
                }
            }
            const float* Bbase = Ws + ((size_t)((l << 8) + k0) << 8);
#pragma unroll
            for (int nt = 0; nt < 4; ++nt) {
                const int ncol = wave * 64 + nt * 16 + laneN;
#pragma unroll
                for (int j = 0; j < 8; ++j) {
                    const float w = Bbase[(j << 8) + ncol];   // Ws[l][k0+j][ncol]
                    const __bf16 h = (__bf16)w;
                    wh8[nt][j] = h;
                    wl8[nt][j] = (__bf16)(w - (float)h);
                }
            }
#pragma unroll
            for (int mt = 0; mt < 2; ++mt)
#pragma unroll
                for (int nt = 0; nt < 4; ++nt) {
                    acc[mt][nt] = __builtin_amdgcn_mfma_f32_16x16x32_bf16(al[mt], wh8[nt], acc[mt][nt], 0, 0, 0);
                    acc[mt][nt] = __builtin_amdgcn_mfma_f32_16x16x32_bf16(ah[mt], wl8[nt], acc[mt][nt], 0, 0, 0);
                    acc[mt][nt] = __builtin_amdgcn_mfma_f32_16x16x32_bf16(ah[mt], wh8[nt], acc[mt][nt], 0, 0, 0);
                }
        }
        __syncthreads();   // all waves done reading xbuf (x_{l-1} dead after this)

        // ---- scatter z1 into xbuf (R5 verbatim)
#pragma unroll
        for (int mt = 0; mt < 2; ++mt)
#pragma unroll
            for (int r = 0; r < 4; ++r) {
                const int m = mt * 16 + kb * 4 + r;
#pragma unroll
                for (int nt = 0; nt < 4; ++nt)
                    xbuf[m][wave * 64 + nt * 16 + laneN] = acc[mt][nt][r];
            }
        __syncthreads();

        // ---- epilogue 1 (thread-per-column, in-place, fast sin)
        {
            float at[8];
#pragma unroll
            for (int f = 0; f < 8; ++f)
                at[f] = ffnA[(l << 11) + (f << 8) + tid] * (float)(1 << l);
            const float bsv = bs[(l << 8) + tid];
#pragma unroll
            for (int m = 0; m < MT; ++m) {
                const f32x4 g0 = *(const f32x4*)&gf[l][m][0];
                const f32x4 g1 = *(const f32x4*)&gf[l][m][4];
                const float g = g0.x * at[0] + g0.y * at[1] + g0.z * at[2] + g0.w * at[3]
                              + g1.x * at[4] + g1.y * at[5] + g1.z * at[6] + g1.w * at[7];
                xbuf[m][tid] = __sinf(xbuf[m][tid] + bsv) + __sinf(TWO_PI * g);
            }
        }
        __syncthreads();   // x_l visible to all waves

        // ===== GEMM2: z2 = X @ Wh[l] =====
        f32x4 acc2[2][4];
#pragma unroll
        for (int mt = 0; mt < 2; ++mt)
#pragma unroll
            for (int nt = 0; nt < 4; ++nt) acc2[mt][nt] = (f32x4)0.0f;

        for (int kt = 0; kt < 8; ++kt) {
            const int k0 = kt * 32 + kb * 8;
            bf16x8 ah[2], al[2], wh8[4], wl8[4];
#pragma unroll
            for (int mt = 0; mt < 2; ++mt) {
                const f32x4 v0 = *(const f32x4*)&xbuf[mt * 16 + laneN][k0];
                const f32x4 v1 = *(const f32x4*)&xbuf[mt * 16 + laneN][k0 + 4];
                const float tmp[8] = {v0.x, v0.y, v0.z, v0.w, v1.x, v1.y, v1.z, v1.w};
#pragma unroll
                for (int j = 0; j < 8; ++j) {
                    const float v = tmp[j];
                    const __bf16 h = (__bf16)v;
                    ah[mt][j] = h;
                    al[mt][j] = (__bf16)(v - (float)h);
                }
            }
            const float* Bbase = Wh + ((size_t)((l << 8) + k0) << 8);
#pragma unroll
            for (int nt = 0; nt < 4; ++nt) {
                const int ncol = wave * 64 + nt * 16 + laneN;
#pragma unroll
                for (int j = 0; j < 8; ++j) {
                    const float w = Bbase[(j << 8) + ncol];   // Wh[l][k0+j][ncol]
                    const __bf16 h = (__bf16)w;
                    wh8[nt][j] = h;
                    wl8[nt][j] = (__bf16)(w - (float)h);
                }
            }
#pragma unroll
            for (int mt = 0; mt < 2; ++mt)
#pragma unroll
                for (int nt = 0; nt < 4; ++nt) {
                    acc2[mt][nt] = __builtin_amdgcn_mfma_f32_16x16x32_bf16(al[mt], wh8[nt], acc2[mt][nt], 0, 0, 0);
                    acc2[mt][nt] = __builtin_amdgcn_mfma_f32_16x16x32_bf16(ah[mt], wl8[nt], acc2[mt][nt], 0, 0, 0);
                    acc2[mt][nt] = __builtin_amdgcn_mfma_f32_16x16x32_bf16(ah[mt], wh8[nt], acc2[mt][nt], 0, 0, 0);
                }
        }
        // z2 stays in registers; x_l stays in xbuf for next layer's GEMM1.

        // ---- epilogue 2 (elementwise, C-layout registers, fast sin)
#pragma unroll
        for (int nt = 0; nt < 4; ++nt) {
            const float bhv = bh[(l << 8) + wave * 64 + nt * 16 + laneN];
#pragma unroll
            for (int mt = 0; mt < 2; ++mt)
#pragma unroll
                for (int r = 0; r < 4; ++r)
                    xout[mt][nt][r] += __sinf(acc2[mt][nt][r] + bhv);
        }
    }

    // ---- store (C/D layout, R5 verbatim)
#pragma unroll
    for (int mt = 0; mt < 2; ++mt)
#pragma unroll
        for (int r = 0; r < 4; ++r) {
            const int m = mt * 16 + kb * 4 + r;
#pragma unroll
            for (int nt = 0; nt < 4; ++nt)
                out[(size_t)(m0 + m) * 256 + wave * 64 + nt * 16 + laneN] = xout[mt][nt][r];
        }
}

// ---------------- launch ---------------------------------------------------
extern "C" void kernel_launch(void* const* d_in, const int* in_sizes, int n_in,
                              void* d_out, int out_size, void* d_ws, size_t ws_size,
                              hipStream_t stream) {
    const float* in_pos = (const float*)d_in[0];
    const float* table  = (const float*)d_in[1];
    const float* ffn_A  = (const float*)d_in[2];
    const float* W0     = (const float*)d_in[3];
    const float* b0     = (const float*)d_in[4];
    const float* Ws     = (const float*)d_in[5];
    const float* bs     = (const float*)d_in[6];
    const float* Wh     = (const float*)d_in[7];
    const float* bh     = (const float*)d_in[8];
    float* out = (float*)d_out;

    ffb_main<<<NPTS / MT, 256, 0, stream>>>(in_pos, table, ffn_A, W0, b0,
                                            Ws, bs, Wh, bh, out);
}

// Round 6
// 1244.679 us; speedup vs baseline: 1.2240x; 1.2240x over previous
//
#include <hip/hip_runtime.h>
#include <hip/hip_bf16.h>
#include <math.h>

typedef __attribute__((ext_vector_type(8))) __bf16 bf16x8;
typedef __attribute__((ext_vector_type(4))) float f32x4;

#define NPTS   131072
#define TBL    32768
#define MT     64
#define TWO_PI 6.28318530717958647692f

// R11: MT 32 -> 64. R10's post-mortem showed the critical path is the scalar
// B-fragment feed (2048 global_load_dword + cvt chains per wave), which is
// per-block constant -- so serve 2x rows per block to halve its per-point
// cost. acc/xout grow to [4][4]; launch_bounds back to (256,2) for VGPR/ILP
// headroom (LDS caps us at 2 blocks/CU anyway). __sinf kept (R10: bit-exact
// absmax vs libm). X-path stays fp32 xbuf (R5-proven).

__global__ __launch_bounds__(256, 2) void ffb_main(
    const float* __restrict__ in_pos, const float* __restrict__ table,
    const float* __restrict__ ffnA, const float* __restrict__ W0,
    const float* __restrict__ b0, const float* __restrict__ Ws,
    const float* __restrict__ bs, const float* __restrict__ Wh,
    const float* __restrict__ bh, float* __restrict__ out)
{
    __shared__ __align__(16) float xbuf[MT][260];   // 66.6 KB
    __shared__ __align__(16) float gf[4][MT][8];    //  8.2 KB
    __shared__ float ptile[MT][3];                  //  0.8 KB

    const int tid   = threadIdx.x;
    const int wave  = tid >> 6;
    const int lane  = tid & 63;
    const int laneN = lane & 15;      // A row m / B col n / D col
    const int kb    = lane >> 4;      // k-octet / D row-quad
    const int m0    = blockIdx.x * MT;

    if (tid < MT * 3) ((float*)ptile)[tid] = in_pos[m0 * 3 + tid];
    __syncthreads();

    // ---- hash-grid encode: one (level, point) per thread (4 x 64 = 256)
    {
        const int l = tid >> 6, m = tid & 63;
        const float px = ptile[m][0], py = ptile[m][1], pz = ptile[m][2];
        const float res = (float)(16 << l);
        const float fx = (px + 1.0f) * 0.5f * res;
        const float fy = (py + 1.0f) * 0.5f * res;
        const float fz = (pz + 1.0f) * 0.5f * res;
        const float f0x = floorf(fx), f0y = floorf(fy), f0z = floorf(fz);
        const float frx = fx - f0x, fry = fy - f0y, frz = fz - f0z;
        const unsigned ux = (unsigned)f0x, uy = (unsigned)f0y, uz = (unsigned)f0z;
        float acc[8];
#pragma unroll
        for (int f = 0; f < 8; ++f) acc[f] = 0.0f;
#pragma unroll
        for (int c = 0; c < 8; ++c) {
            const unsigned cx = ux + ((c >> 2) & 1);
            const unsigned cy = uy + ((c >> 1) & 1);
            const unsigned cz = uz + (c & 1);
            const unsigned id = (cx * 1u ^ cy * 2654435761u ^ cz * 805459861u) & (TBL - 1);
            const float4* tp = (const float4*)(table + ((size_t)(l * TBL + id) << 3));
            const float4 t0 = tp[0], t1 = tp[1];
            const float wx = (c & 4) ? frx : 1.0f - frx;
            const float wy = (c & 2) ? fry : 1.0f - fry;
            const float wz = (c & 1) ? frz : 1.0f - frz;
            const float w = wx * wy * wz;
            acc[0] += w * t0.x; acc[1] += w * t0.y; acc[2] += w * t0.z; acc[3] += w * t0.w;
            acc[4] += w * t1.x; acc[5] += w * t1.y; acc[6] += w * t1.z; acc[7] += w * t1.w;
        }
#pragma unroll
        for (int f = 0; f < 8; ++f) gf[l][m][f] = acc[f];
    }

    // ---- layer 0 (thread-per-column, fast sin)
    {
        const float w0 = W0[tid], w1 = W0[256 + tid], w2 = W0[512 + tid], bb = b0[tid];
#pragma unroll 4
        for (int m = 0; m < MT; ++m)
            xbuf[m][tid] = __sinf(ptile[m][0] * w0 + ptile[m][1] * w1 + ptile[m][2] * w2 + bb);
    }
    __syncthreads();

    f32x4 xout[4][4];
#pragma unroll
    for (int mt = 0; mt < 4; ++mt)
#pragma unroll
        for (int nt = 0; nt < 4; ++nt) xout[mt][nt] = (f32x4)0.0f;

    for (int l = 0; l < 4; ++l) {
        // ===== GEMM1: z1 = X @ Ws[l], split-bf16 MFMA, W from original layout
        f32x4 acc[4][4];
#pragma unroll
        for (int mt = 0; mt < 4; ++mt)
#pragma unroll
            for (int nt = 0; nt < 4; ++nt) acc[mt][nt] = (f32x4)0.0f;

        for (int kt = 0; kt < 8; ++kt) {
            const int k0 = kt * 32 + kb * 8;
            bf16x8 ah[4], al[4], wh8[4], wl8[4];
#pragma unroll
            for (int mt = 0; mt < 4; ++mt) {
                const f32x4 v0 = *(const f32x4*)&xbuf[mt * 16 + laneN][k0];
                const f32x4 v1 = *(const f32x4*)&xbuf[mt * 16 + laneN][k0 + 4];
                const float tmp[8] = {v0.x, v0.y, v0.z, v0.w, v1.x, v1.y, v1.z, v1.w};
#pragma unroll
                for (int j = 0; j < 8; ++j) {
                    const float v = tmp[j];
                    const __bf16 h = (__bf16)v;
                    ah[mt][j] = h;
                    al[mt][j] = (__bf16)(v - (float)h);
                }
            }
            const float* Bbase = Ws + ((size_t)((l << 8) + k0) << 8);
#pragma unroll
            for (int nt = 0; nt < 4; ++nt) {
                const int ncol = wave * 64 + nt * 16 + laneN;
#pragma unroll
                for (int j = 0; j < 8; ++j) {
                    const float w = Bbase[(j << 8) + ncol];   // Ws[l][k0+j][ncol]
                    const __bf16 h = (__bf16)w;
                    wh8[nt][j] = h;
                    wl8[nt][j] = (__bf16)(w - (float)h);
                }
            }
#pragma unroll
            for (int mt = 0; mt < 4; ++mt)
#pragma unroll
                for (int nt = 0; nt < 4; ++nt) {
                    acc[mt][nt] = __builtin_amdgcn_mfma_f32_16x16x32_bf16(al[mt], wh8[nt], acc[mt][nt], 0, 0, 0);
                    acc[mt][nt] = __builtin_amdgcn_mfma_f32_16x16x32_bf16(ah[mt], wl8[nt], acc[mt][nt], 0, 0, 0);
                    acc[mt][nt] = __builtin_amdgcn_mfma_f32_16x16x32_bf16(ah[mt], wh8[nt], acc[mt][nt], 0, 0, 0);
                }
        }
        __syncthreads();   // all waves done reading xbuf (x_{l-1} dead after this)

        // ---- scatter z1 into xbuf (C/D layout)
#pragma unroll
        for (int mt = 0; mt < 4; ++mt)
#pragma unroll
            for (int r = 0; r < 4; ++r) {
                const int m = mt * 16 + kb * 4 + r;
#pragma unroll
                for (int nt = 0; nt < 4; ++nt)
                    xbuf[m][wave * 64 + nt * 16 + laneN] = acc[mt][nt][r];
            }
        __syncthreads();

        // ---- epilogue 1 (thread-per-column, in-place, fast sin)
        {
            float at[8];
#pragma unroll
            for (int f = 0; f < 8; ++f)
                at[f] = ffnA[(l << 11) + (f << 8) + tid] * (float)(1 << l);
            const float bsv = bs[(l << 8) + tid];
#pragma unroll 4
            for (int m = 0; m < MT; ++m) {
                const f32x4 g0 = *(const f32x4*)&gf[l][m][0];
                const f32x4 g1 = *(const f32x4*)&gf[l][m][4];
                const float g = g0.x * at[0] + g0.y * at[1] + g0.z * at[2] + g0.w * at[3]
                              + g1.x * at[4] + g1.y * at[5] + g1.z * at[6] + g1.w * at[7];
                xbuf[m][tid] = __sinf(xbuf[m][tid] + bsv) + __sinf(TWO_PI * g);
            }
        }
        __syncthreads();   // x_l visible to all waves

        // ===== GEMM2: z2 = X @ Wh[l] =====
        f32x4 acc2[4][4];
#pragma unroll
        for (int mt = 0; mt < 4; ++mt)
#pragma unroll
            for (int nt = 0; nt < 4; ++nt) acc2[mt][nt] = (f32x4)0.0f;

        for (int kt = 0; kt < 8; ++kt) {
            const int k0 = kt * 32 + kb * 8;
            bf16x8 ah[4], al[4], wh8[4], wl8[4];
#pragma unroll
            for (int mt = 0; mt < 4; ++mt) {
                const f32x4 v0 = *(const f32x4*)&xbuf[mt * 16 + laneN][k0];
                const f32x4 v1 = *(const f32x4*)&xbuf[mt * 16 + laneN][k0 + 4];
                const float tmp[8] = {v0.x, v0.y, v0.z, v0.w, v1.x, v1.y, v1.z, v1.w};
#pragma unroll
                for (int j = 0; j < 8; ++j) {
                    const float v = tmp[j];
                    const __bf16 h = (__bf16)v;
                    ah[mt][j] = h;
                    al[mt][j] = (__bf16)(v - (float)h);
                }
            }
            const float* Bbase = Wh + ((size_t)((l << 8) + k0) << 8);
#pragma unroll
            for (int nt = 0; nt < 4; ++nt) {
                const int ncol = wave * 64 + nt * 16 + laneN;
#pragma unroll
                for (int j = 0; j < 8; ++j) {
                    const float w = Bbase[(j << 8) + ncol];   // Wh[l][k0+j][ncol]
                    const __bf16 h = (__bf16)w;
                    wh8[nt][j] = h;
                    wl8[nt][j] = (__bf16)(w - (float)h);
                }
            }
#pragma unroll
            for (int mt = 0; mt < 4; ++mt)
#pragma unroll
                for (int nt = 0; nt < 4; ++nt) {
                    acc2[mt][nt] = __builtin_amdgcn_mfma_f32_16x16x32_bf16(al[mt], wh8[nt], acc2[mt][nt], 0, 0, 0);
                    acc2[mt][nt] = __builtin_amdgcn_mfma_f32_16x16x32_bf16(ah[mt], wl8[nt], acc2[mt][nt], 0, 0, 0);
                    acc2[mt][nt] = __builtin_amdgcn_mfma_f32_16x16x32_bf16(ah[mt], wh8[nt], acc2[mt][nt], 0, 0, 0);
                }
        }
        // z2 stays in registers; x_l stays in xbuf for next layer's GEMM1.

        // ---- epilogue 2 (elementwise, C-layout registers, fast sin)
#pragma unroll
        for (int nt = 0; nt < 4; ++nt) {
            const float bhv = bh[(l << 8) + wave * 64 + nt * 16 + laneN];
#pragma unroll
            for (int mt = 0; mt < 4; ++mt)
#pragma unroll
                for (int r = 0; r < 4; ++r)
                    xout[mt][nt][r] += __sinf(acc2[mt][nt][r] + bhv);
        }
    }

    // ---- store (C/D layout)
#pragma unroll
    for (int mt = 0; mt < 4; ++mt)
#pragma unroll
        for (int r = 0; r < 4; ++r) {
            const int m = mt * 16 + kb * 4 + r;
#pragma unroll
            for (int nt = 0; nt < 4; ++nt)
                out[(size_t)(m0 + m) * 256 + wave * 64 + nt * 16 + laneN] = xout[mt][nt][r];
        }
}

// ---------------- launch ---------------------------------------------------
extern "C" void kernel_launch(void* const* d_in, const int* in_sizes, int n_in,
                              void* d_out, int out_size, void* d_ws, size_t ws_size,
                              hipStream_t stream) {
    const float* in_pos = (const float*)d_in[0];
    const float* table  = (const float*)d_in[1];
    const float* ffn_A  = (const float*)d_in[2];
    const float* W0     = (const float*)d_in[3];
    const float* b0     = (const float*)d_in[4];
    const float* Ws     = (const float*)d_in[5];
    const float* bs     = (const float*)d_in[6];
    const float* Wh     = (const float*)d_in[7];
    const float* bh     = (const float*)d_in[8];
    float* out = (float*)d_out;

    ffb_main<<<NPTS / MT, 256, 0, stream>>>(in_pos, table, ffn_A, W0, b0,
                                            Ws, bs, Wh, bh, out);
}

// Round 11
// 645.662 us; speedup vs baseline: 2.3596x; 1.9278x over previous
//
#include <hip/hip_runtime.h>
#include <hip/hip_bf16.h>
#include <math.h>

typedef __attribute__((ext_vector_type(8))) __bf16 bf16x8;
typedef __attribute__((ext_vector_type(4))) float f32x4;

#define NPTS   131072
#define TBL    32768
#define MT     64
#define TWO_PI 6.28318530717958647692f

// R16: R11 + ONLY the bf16 hi/lo X-buffer (the last untested ingredient).
// Failure map: weight table (R8) FAIL; register weight-prefetch (R13 bf16,
// R15 fp32) FAIL; both parked permanently. bf16-LDS-X was only ever bundled
// with those (R7/R12) -- isolated here on the proven R11 scaffold.
//  - X stored as xhi/xlo[64][272] (544B row stride: 16B-aligned b128 reads,
//    <=2-way bank conflicts). Split once at write (layer0/scatter/epilogue1)
//    with R11's exact RNE expressions -> A-fragments bit-identical.
//  - Weight path, kt loops (no prefetch/persistence), epilogues, barriers:
//    verbatim R11 (1180us passing). z1 bf16-pair round-trip adds ~2^-17 rel.

__global__ __launch_bounds__(256, 2) void ffb_main(
    const float* __restrict__ in_pos, const float* __restrict__ table,
    const float* __restrict__ ffnA, const float* __restrict__ W0,
    const float* __restrict__ b0, const float* __restrict__ Ws,
    const float* __restrict__ bs, const float* __restrict__ Wh,
    const float* __restrict__ bh, float* __restrict__ out)
{
    __shared__ __align__(16) __bf16 xhi[MT][272];   // 34.8 KB
    __shared__ __align__(16) __bf16 xlo[MT][272];   // 34.8 KB
    __shared__ __align__(16) float gf[4][MT][8];    //  8.2 KB
    __shared__ float ptile[MT][3];                  //  0.8 KB

    const int tid   = threadIdx.x;
    const int wave  = tid >> 6;
    const int lane  = tid & 63;
    const int laneN = lane & 15;      // A row m / B col n / D col
    const int kb    = lane >> 4;      // k-octet / D row-quad
    const int m0    = blockIdx.x * MT;

    if (tid < MT * 3) ((float*)ptile)[tid] = in_pos[m0 * 3 + tid];
    __syncthreads();

    // ---- hash-grid encode: one (level, point) per thread (4 x 64 = 256)
    {
        const int l = tid >> 6, m = tid & 63;
        const float px = ptile[m][0], py = ptile[m][1], pz = ptile[m][2];
        const float res = (float)(16 << l);
        const float fx = (px + 1.0f) * 0.5f * res;
        const float fy = (py + 1.0f) * 0.5f * res;
        const float fz = (pz + 1.0f) * 0.5f * res;
        const float f0x = floorf(fx), f0y = floorf(fy), f0z = floorf(fz);
        const float frx = fx - f0x, fry = fy - f0y, frz = fz - f0z;
        const unsigned ux = (unsigned)f0x, uy = (unsigned)f0y, uz = (unsigned)f0z;
        float acc[8];
#pragma unroll
        for (int f = 0; f < 8; ++f) acc[f] = 0.0f;
#pragma unroll
        for (int c = 0; c < 8; ++c) {
            const unsigned cx = ux + ((c >> 2) & 1);
            const unsigned cy = uy + ((c >> 1) & 1);
            const unsigned cz = uz + (c & 1);
            const unsigned id = (cx * 1u ^ cy * 2654435761u ^ cz * 805459861u) & (TBL - 1);
            const float4* tp = (const float4*)(table + ((size_t)(l * TBL + id) << 3));
            const float4 t0 = tp[0], t1 = tp[1];
            const float wx = (c & 4) ? frx : 1.0f - frx;
            const float wy = (c & 2) ? fry : 1.0f - fry;
            const float wz = (c & 1) ? frz : 1.0f - frz;
            const float w = wx * wy * wz;
            acc[0] += w * t0.x; acc[1] += w * t0.y; acc[2] += w * t0.z; acc[3] += w * t0.w;
            acc[4] += w * t1.x; acc[5] += w * t1.y; acc[6] += w * t1.z; acc[7] += w * t1.w;
        }
#pragma unroll
        for (int f = 0; f < 8; ++f) gf[l][m][f] = acc[f];
    }

    // ---- layer 0 (thread-per-column, fast sin, split at write)
    {
        const float w0 = W0[tid], w1 = W0[256 + tid], w2 = W0[512 + tid], bb = b0[tid];
#pragma unroll 4
        for (int m = 0; m < MT; ++m) {
            const float v = __sinf(ptile[m][0] * w0 + ptile[m][1] * w1 + ptile[m][2] * w2 + bb);
            const __bf16 h = (__bf16)v;
            xhi[m][tid] = h;
            xlo[m][tid] = (__bf16)(v - (float)h);
        }
    }
    __syncthreads();

    f32x4 xout[4][4];
#pragma unroll
    for (int mt = 0; mt < 4; ++mt)
#pragma unroll
        for (int nt = 0; nt < 4; ++nt) xout[mt][nt] = (f32x4)0.0f;

    for (int l = 0; l < 4; ++l) {
        // ===== GEMM1: z1 = X @ Ws[l]; A from pre-split LDS, W verbatim R11
        f32x4 acc[4][4];
#pragma unroll
        for (int mt = 0; mt < 4; ++mt)
#pragma unroll
            for (int nt = 0; nt < 4; ++nt) acc[mt][nt] = (f32x4)0.0f;

        for (int kt = 0; kt < 8; ++kt) {
            const int k0 = kt * 32 + kb * 8;
            bf16x8 ah[4], al[4], wh8[4], wl8[4];
#pragma unroll
            for (int mt = 0; mt < 4; ++mt) {
                ah[mt] = *(const bf16x8*)&xhi[mt * 16 + laneN][k0];
                al[mt] = *(const bf16x8*)&xlo[mt * 16 + laneN][k0];
            }
            const float* Bbase = Ws + ((size_t)((l << 8) + k0) << 8);
#pragma unroll
            for (int nt = 0; nt < 4; ++nt) {
                const int ncol = wave * 64 + nt * 16 + laneN;
#pragma unroll
                for (int j = 0; j < 8; ++j) {
                    const float w = Bbase[(j << 8) + ncol];   // Ws[l][k0+j][ncol]
                    const __bf16 h = (__bf16)w;
                    wh8[nt][j] = h;
                    wl8[nt][j] = (__bf16)(w - (float)h);
                }
            }
#pragma unroll
            for (int mt = 0; mt < 4; ++mt)
#pragma unroll
                for (int nt = 0; nt < 4; ++nt) {
                    acc[mt][nt] = __builtin_amdgcn_mfma_f32_16x16x32_bf16(al[mt], wh8[nt], acc[mt][nt], 0, 0, 0);
                    acc[mt][nt] = __builtin_amdgcn_mfma_f32_16x16x32_bf16(ah[mt], wl8[nt], acc[mt][nt], 0, 0, 0);
                    acc[mt][nt] = __builtin_amdgcn_mfma_f32_16x16x32_bf16(ah[mt], wh8[nt], acc[mt][nt], 0, 0, 0);
                }
        }
        __syncthreads();   // all waves done reading x_{l-1}

        // ---- scatter z1 (C/D layout) as bf16 hi/lo
#pragma unroll
        for (int mt = 0; mt < 4; ++mt)
#pragma unroll
            for (int r = 0; r < 4; ++r) {
                const int m = mt * 16 + kb * 4 + r;
#pragma unroll
                for (int nt = 0; nt < 4; ++nt) {
                    const int ncol = wave * 64 + nt * 16 + laneN;
                    const float z = acc[mt][nt][r];
                    const __bf16 h = (__bf16)z;
                    xhi[m][ncol] = h;
                    xlo[m][ncol] = (__bf16)(z - (float)h);
                }
            }
        __syncthreads();

        // ---- epilogue 1 (thread-per-column, in-place, fast sin)
        {
            float at[8];
#pragma unroll
            for (int f = 0; f < 8; ++f)
                at[f] = ffnA[(l << 11) + (f << 8) + tid] * (float)(1 << l);
            const float bsv = bs[(l << 8) + tid];
#pragma unroll 4
            for (int m = 0; m < MT; ++m) {
                const f32x4 g0 = *(const f32x4*)&gf[l][m][0];
                const f32x4 g1 = *(const f32x4*)&gf[l][m][4];
                const float g = g0.x * at[0] + g0.y * at[1] + g0.z * at[2] + g0.w * at[3]
                              + g1.x * at[4] + g1.y * at[5] + g1.z * at[6] + g1.w * at[7];
                const float z1 = (float)xhi[m][tid] + (float)xlo[m][tid];
                const float v = __sinf(z1 + bsv) + __sinf(TWO_PI * g);
                const __bf16 h = (__bf16)v;
                xhi[m][tid] = h;
                xlo[m][tid] = (__bf16)(v - (float)h);
            }
        }
        __syncthreads();   // x_l visible to all waves

        // ===== GEMM2: z2 = X @ Wh[l] =====
        f32x4 acc2[4][4];
#pragma unroll
        for (int mt = 0; mt < 4; ++mt)
#pragma unroll
            for (int nt = 0; nt < 4; ++nt) acc2[mt][nt] = (f32x4)0.0f;

        for (int kt = 0; kt < 8; ++kt) {
            const int k0 = kt * 32 + kb * 8;
            bf16x8 ah[4], al[4], wh8[4], wl8[4];
#pragma unroll
            for (int mt = 0; mt < 4; ++mt) {
                ah[mt] = *(const bf16x8*)&xhi[mt * 16 + laneN][k0];
                al[mt] = *(const bf16x8*)&xlo[mt * 16 + laneN][k0];
            }
            const float* Bbase = Wh + ((size_t)((l << 8) + k0) << 8);
#pragma unroll
            for (int nt = 0; nt < 4; ++nt) {
                const int ncol = wave * 64 + nt * 16 + laneN;
#pragma unroll
                for (int j = 0; j < 8; ++j) {
                    const float w = Bbase[(j << 8) + ncol];   // Wh[l][k0+j][ncol]
                    const __bf16 h = (__bf16)w;
                    wh8[nt][j] = h;
                    wl8[nt][j] = (__bf16)(w - (float)h);
                }
            }
#pragma unroll
            for (int mt = 0; mt < 4; ++mt)
#pragma unroll
                for (int nt = 0; nt < 4; ++nt) {
                    acc2[mt][nt] = __builtin_amdgcn_mfma_f32_16x16x32_bf16(al[mt], wh8[nt], acc2[mt][nt], 0, 0, 0);
                    acc2[mt][nt] = __builtin_amdgcn_mfma_f32_16x16x32_bf16(ah[mt], wl8[nt], acc2[mt][nt], 0, 0, 0);
                    acc2[mt][nt] = __builtin_amdgcn_mfma_f32_16x16x32_bf16(ah[mt], wh8[nt], acc2[mt][nt], 0, 0, 0);
                }
        }
        // z2 stays in registers; x_l stays in xhi/xlo for next layer's GEMM1.

        // ---- epilogue 2 (elementwise, C-layout registers, fast sin)
#pragma unroll
        for (int nt = 0; nt < 4; ++nt) {
            const float bhv = bh[(l << 8) + wave * 64 + nt * 16 + laneN];
#pragma unroll
            for (int mt = 0; mt < 4; ++mt)
#pragma unroll
                for (int r = 0; r < 4; ++r)
                    xout[mt][nt][r] += __sinf(acc2[mt][nt][r] + bhv);
        }
    }

    // ---- store (C/D layout)
#pragma unroll
    for (int mt = 0; mt < 4; ++mt)
#pragma unroll
        for (int r = 0; r < 4; ++r) {
            const int m = mt * 16 + kb * 4 + r;
#pragma unroll
            for (int nt = 0; nt < 4; ++nt)
                out[(size_t)(m0 + m) * 256 + wave * 64 + nt * 16 + laneN] = xout[mt][nt][r];
        }
}

// ---------------- launch ---------------------------------------------------
extern "C" void kernel_launch(void* const* d_in, const int* in_sizes, int n_in,
                              void* d_out, int out_size, void* d_ws, size_t ws_size,
                              hipStream_t stream) {
    const float* in_pos = (const float*)d_in[0];
    const float* table  = (const float*)d_in[1];
    const float* ffn_A  = (const float*)d_in[2];
    const float* W0     = (const float*)d_in[3];
    const float* b0     = (const float*)d_in[4];
    const float* Ws     = (const float*)d_in[5];
    const float* bs     = (const float*)d_in[6];
    const float* Wh     = (const float*)d_in[7];
    const float* bh     = (const float*)d_in[8];
    float* out = (float*)d_out;

    ffb_main<<<NPTS / MT, 256, 0, stream>>>(in_pos, table, ffn_A, W0, b0,
                                            Ws, bs, Wh, bh, out);
}